// Round 6
// baseline (1140.733 us; speedup 1.0000x reference)
//
#include <hip/hip_runtime.h>
#include <hip/hip_fp16.h>
#include <math.h>

#define BATCH 48
#define HH 128
#define WW 128
#define HW (128*128)
#define SZ (48*16*HW)          // element count of a 16-ch feature map (fp32-slot sized regions)
#define EPS 1e-5f

// ---- fp16 vector helpers (storage fp16, compute fp32) ----
struct __align__(8)  h4 { __half2 a, b; };
struct __align__(16) h8 { __half2 a, b, c, d; };

__device__ __forceinline__ float4 h4f(h4 v) {
    float2 f0 = __half22float2(v.a), f1 = __half22float2(v.b);
    return make_float4(f0.x, f0.y, f1.x, f1.y);
}
__device__ __forceinline__ h4 f4h(float4 v) {
    h4 r; r.a = __floats2half2_rn(v.x, v.y); r.b = __floats2half2_rn(v.z, v.w); return r;
}

// mish(x) = x*tanh(softplus(x)) = x * t(t+2)/(t(t+2)+2), t = e^x  (exact identity)
__device__ __forceinline__ float mishf(float v) {
    float t = __expf(fminf(v, 20.f));
    float u = t * (t + 2.f);
    return v * (u / (u + 2.f));
}

// XCD-affinity decode: linear block L -> (xcd = L&7) owns batches b == xcd (mod 8).
__device__ __forceinline__ void xcd_decode(int L, int bpb, int& b, int& w) {
    int xcd = L & 7;
    int j   = L >> 3;
    b = xcd + 8 * (j / bpb);
    w = j - (j / bpb) * bpb;
}

// ---------------- K1: 1x1 conv 32->16 (high_fea -> in0 fp16) + weight transposes ----------------
// grid 768 = 48 b * 16 blocks; XCD-sharded. Chunk-4 double-buffered ci prefetch:
// 4 plane loads issued as a burst one full chunk (~512 cy of FMAs) before use.
__global__ __launch_bounds__(256) void k_c0(const float* __restrict__ x,
                                            const float* __restrict__ W,
                                            const float* __restrict__ Wc1,
                                            const float* __restrict__ Wc2,
                                            const float* __restrict__ Wref,
                                            float* __restrict__ WTb,   // 1152 floats
                                            float* __restrict__ WTr,   // 2304 floats
                                            __half* __restrict__ out) {
    __shared__ float w[16*32];
    int tid = threadIdx.x;
    for (int i = tid; i < 512; i += 256) w[i] = W[i];
    if (blockIdx.x == 0) {
        for (int i = tid; i < 576; i += 256) {
            int co = i & 7; int t = i >> 3; int kyx = t % 9; int ci = t / 9;
            WTb[(ci*9 + kyx)*8 + co]       = Wc1[(co*8 + ci)*9 + kyx];
            WTb[576 + (ci*9 + kyx)*8 + co] = Wc2[(co*8 + ci)*9 + kyx];
        }
        for (int i = tid; i < 2304; i += 256) {
            int co = i & 7; int t = i >> 3; int kyx = t % 9; int cih = t / 9;  // 0..31
            int ci = cih & 15; int h = cih >> 4;
            WTr[((h*16 + ci)*9 + kyx)*8 + co] = Wref[((h*8 + co)*16 + ci)*9 + kyx];
        }
    }
    __syncthreads();
    int b, wblk;
    xcd_decode(blockIdx.x, 16, b, wblk);
    int off = ((wblk*256 + tid) << 2);       // 4 px per thread
    const float* xb = x + (size_t)b * 32 * HW + off;
    float acc[16][4];
    #pragma unroll
    for (int c = 0; c < 16; ++c) { acc[c][0]=acc[c][1]=acc[c][2]=acc[c][3]=0.f; }

    float4 A0,A1,A2,A3, B0,B1,B2,B3;
    auto LD4 = [&](int c4, float4& d0, float4& d1, float4& d2, float4& d3) {
        const float* p = xb + (size_t)(c4*4) * HW;
        d0 = *(const float4*)p; d1 = *(const float4*)(p + HW);
        d2 = *(const float4*)(p + 2*HW); d3 = *(const float4*)(p + 3*HW);
    };
    auto CONS = [&](int c4, float4 d0, float4 d1, float4 d2, float4 d3) {
        float4 xv[4] = {d0, d1, d2, d3};
        #pragma unroll
        for (int k = 0; k < 4; ++k) {
            int ci = c4*4 + k;
            #pragma unroll
            for (int co = 0; co < 16; ++co) {
                float wv = w[co*32 + ci];
                acc[co][0] += wv*xv[k].x; acc[co][1] += wv*xv[k].y;
                acc[co][2] += wv*xv[k].z; acc[co][3] += wv*xv[k].w;
            }
        }
    };

    LD4(0, A0,A1,A2,A3);
    #pragma unroll 1
    for (int c4 = 0; c4 < 8; c4 += 2) {
        LD4(c4+1, B0,B1,B2,B3);
        CONS(c4, A0,A1,A2,A3);
        if (c4 + 2 < 8) LD4(c4+2, A0,A1,A2,A3);
        CONS(c4+1, B0,B1,B2,B3);
    }

    __half* ob = out + (size_t)b * 16 * HW + off;
    #pragma unroll
    for (int co = 0; co < 16; ++co)
        *(h4*)(ob + (size_t)co * HW) = f4h(make_float4(acc[co][0],acc[co][1],acc[co][2],acc[co][3]));
}

// -------- direct-from-global 3x3 conv, fp16 in/out, 4 px/thread, 1-ci-ahead ping-pong --------
// Tile 128 wide x 4 tall, 128 threads (tx 0..31, ty 0..3). Per (ci,ky): 3 h4 loads (window
// tx*4-4 .. +11) feeding 96 fp32 FMAs. P/Q ping-pong: ci+1's 3 groups load while ci computes
// -> load->use distance = 3 FMA-groups (~650 cy). No register copies.
template<int D, int NCI>
__device__ __forceinline__ void dconv4(const __half* __restrict__ base,  // NCI ch planes
                                       const float* __restrict__ wb,     // NCI*72 [ci][kyx][co8]
                                       const __half* __restrict__ zh,    // >=16 zeroed halfs
                                       __half* __restrict__ obase,       // 8 ch planes
                                       float* __restrict__ statp,        // 2 floats
                                       int y0, int tid) {
    int tx = tid & 31, ty = tid >> 5;      // 32 x 4
    int y  = y0 + ty;
    int xg = tx*4 - 4;                     // leftmost loaded element (mult of 4)
    bool mx0 = (tx > 0);                   // h4 @ xg
    bool mx2 = (tx < 31);                  // h4 @ xg+8
    bool my[3];
    #pragma unroll
    for (int ky = 0; ky < 3; ++ky) my[ky] = ((unsigned)(y + D*(ky-1)) < 128u);

    float acc[8][4];
    #pragma unroll
    for (int c = 0; c < 8; ++c) { acc[c][0]=acc[c][1]=acc[c][2]=acc[c][3]=0.f; }

    h4 P0a,P0b,P0c, P1a,P1b,P1c, P2a,P2b,P2c;
    h4 Q0a,Q0b,Q0c, Q1a,Q1b,Q1c, Q2a,Q2b,Q2c;

    auto LD = [&](const __half* cb, int ky, h4& d0, h4& d1, h4& d2) {
        const __half* rp = cb + (y + D*(ky-1))*WW;
        bool m = my[ky];
        d0 = *(const h4*)((m && mx0) ? rp     : zh);
        d1 = *(const h4*)( m         ? rp + 4 : zh);
        d2 = *(const h4*)((m && mx2) ? rp + 8 : zh);
    };
    auto FMAG = [&](const float* wp, h4 d0, h4 d1, h4 d2) {
        float4 f0 = h4f(d0), f1 = h4f(d1), f2 = h4f(d2);
        float u[12] = {f0.x,f0.y,f0.z,f0.w, f1.x,f1.y,f1.z,f1.w, f2.x,f2.y,f2.z,f2.w};
        #pragma unroll
        for (int kx = 0; kx < 3; ++kx) {
            const float* wq = wp + kx*8;
            float w0 = wq[0], w1 = wq[1], w2 = wq[2], w3 = wq[3];
            float w4 = wq[4], w5 = wq[5], w6 = wq[6], w7 = wq[7];
            #pragma unroll
            for (int j = 0; j < 4; ++j) {
                float xv = u[4 - D + D*kx + j];
                acc[0][j] += w0*xv; acc[1][j] += w1*xv;
                acc[2][j] += w2*xv; acc[3][j] += w3*xv;
                acc[4][j] += w4*xv; acc[5][j] += w5*xv;
                acc[6][j] += w6*xv; acc[7][j] += w7*xv;
            }
        }
    };

    const __half* cb = base + xg;
    const float* wp = wb;
    LD(cb, 0, P0a,P0b,P0c);
    LD(cb, 1, P1a,P1b,P1c);
    LD(cb, 2, P2a,P2b,P2c);
    #pragma unroll 1
    for (int ci = 0; ci < NCI; ci += 2) {
        const __half* cb1 = cb + HW;
        const __half* cb2 = cb + 2*HW;
        bool more = (ci + 2 < NCI);
        LD(cb1, 0, Q0a,Q0b,Q0c);
        FMAG(wp,       P0a,P0b,P0c);
        LD(cb1, 1, Q1a,Q1b,Q1c);
        FMAG(wp + 24,  P1a,P1b,P1c);
        LD(cb1, 2, Q2a,Q2b,Q2c);
        FMAG(wp + 48,  P2a,P2b,P2c);
        if (more) LD(cb2, 0, P0a,P0b,P0c);
        FMAG(wp + 72,  Q0a,Q0b,Q0c);
        if (more) LD(cb2, 1, P1a,P1b,P1c);
        FMAG(wp + 96,  Q1a,Q1b,Q1c);
        if (more) LD(cb2, 2, P2a,P2b,P2c);
        FMAG(wp + 120, Q2a,Q2b,Q2c);
        cb += 2*HW; wp += 144;
    }

    // ---- write (fp16) + GN partial stats (fp32) ----
    float s = 0.f, q = 0.f;
    __half* ob = obase + y*WW + tx*4;
    #pragma unroll
    for (int c = 0; c < 8; ++c) {
        *(h4*)(ob + (size_t)c*HW) = f4h(make_float4(acc[c][0],acc[c][1],acc[c][2],acc[c][3]));
        #pragma unroll
        for (int j = 0; j < 4; ++j) { s += acc[c][j]; q += acc[c][j]*acc[c][j]; }
    }
    #pragma unroll
    for (int o = 32; o > 0; o >>= 1) { s += __shfl_down(s,o); q += __shfl_down(q,o); }
    if ((tid & 63) == 0) { atomicAdd(&statp[0], s); atomicAdd(&statp[1], q); }
}

// ---------------- K2: dual-branch 3x3; flat grid 3072, XCD-sharded ----------------
// per batch: 64 blocks = 2 branch * 32 yblk (4 rows each)
__global__ __launch_bounds__(128) void k_branch6(const __half* __restrict__ in0,
                                                 const float* __restrict__ WTb,
                                                 const __half* __restrict__ zh,
                                                 __half* __restrict__ outp,
                                                 float* __restrict__ stat) {
    int b, w;
    xcd_decode(blockIdx.x, 64, b, w);
    int br = w >> 5;
    int y0 = (w & 31) << 2;
    int tid = threadIdx.x;
    if (br == 0) {
        dconv4<1,8>(in0 + (size_t)(b*16    )*HW, WTb,       zh,
                    outp + (size_t)(b*16    )*HW, stat + b*2, y0, tid);
    } else {
        dconv4<2,8>(in0 + (size_t)(b*16 + 8)*HW, WTb + 576, zh,
                    outp + (size_t)(b*16 + 8)*HW, stat + b*2, y0, tid);
    }
}

// ---------------- K3: 1x1 conv 24->16 (low, fp16 out) + GN(groups=2) stats ----------------
// grid 768; chunk-4 double-buffered ci prefetch (6 chunks).
__global__ __launch_bounds__(256) void k_low(const float* __restrict__ x,
                                             const float* __restrict__ W,
                                             __half* __restrict__ outp,
                                             float* __restrict__ stat) {
    __shared__ float w[16*24];
    int tid = threadIdx.x;
    for (int i = tid; i < 384; i += 256) w[i] = W[i];
    __syncthreads();
    int b, wblk;
    xcd_decode(blockIdx.x, 16, b, wblk);
    int off = ((wblk*256 + tid) << 2);
    const float* xb = x + (size_t)b * 24 * HW + off;
    float acc[16][4];
    #pragma unroll
    for (int c = 0; c < 16; ++c) { acc[c][0]=acc[c][1]=acc[c][2]=acc[c][3]=0.f; }

    float4 A0,A1,A2,A3, B0,B1,B2,B3;
    auto LD4 = [&](int c4, float4& d0, float4& d1, float4& d2, float4& d3) {
        const float* p = xb + (size_t)(c4*4) * HW;
        d0 = *(const float4*)p; d1 = *(const float4*)(p + HW);
        d2 = *(const float4*)(p + 2*HW); d3 = *(const float4*)(p + 3*HW);
    };
    auto CONS = [&](int c4, float4 d0, float4 d1, float4 d2, float4 d3) {
        float4 xv[4] = {d0, d1, d2, d3};
        #pragma unroll
        for (int k = 0; k < 4; ++k) {
            int ci = c4*4 + k;
            #pragma unroll
            for (int co = 0; co < 16; ++co) {
                float wv = w[co*24 + ci];
                acc[co][0] += wv*xv[k].x; acc[co][1] += wv*xv[k].y;
                acc[co][2] += wv*xv[k].z; acc[co][3] += wv*xv[k].w;
            }
        }
    };

    LD4(0, A0,A1,A2,A3);
    #pragma unroll 1
    for (int c4 = 0; c4 < 6; c4 += 2) {
        LD4(c4+1, B0,B1,B2,B3);
        CONS(c4, A0,A1,A2,A3);
        if (c4 + 2 < 6) LD4(c4+2, A0,A1,A2,A3);
        CONS(c4+1, B0,B1,B2,B3);
    }

    __half* ob = outp + (size_t)b * 16 * HW + off;
    float s0=0.f,q0=0.f,s1=0.f,q1=0.f;
    #pragma unroll
    for (int co = 0; co < 16; ++co) {
        *(h4*)(ob + (size_t)co * HW) = f4h(make_float4(acc[co][0],acc[co][1],acc[co][2],acc[co][3]));
        #pragma unroll
        for (int j = 0; j < 4; ++j) {
            if (co < 8) { s0 += acc[co][j]; q0 += acc[co][j]*acc[co][j]; }
            else        { s1 += acc[co][j]; q1 += acc[co][j]*acc[co][j]; }
        }
    }
    #pragma unroll
    for (int o = 32; o > 0; o >>= 1) {
        s0 += __shfl_down(s0,o); q0 += __shfl_down(q0,o);
        s1 += __shfl_down(s1,o); q1 += __shfl_down(q1,o);
    }
    if ((tid & 63) == 0) {
        atomicAdd(&stat[b*4+0], s0); atomicAdd(&stat[b*4+1], q0);
        atomicAdd(&stat[b*4+2], s1); atomicAdd(&stat[b*4+3], q1);
    }
}

// ---------------- K4: GN-apply (high & low) + add + mish; 8 px/thread, fp16 ----------------
// grid 6144 = 48 b * 128 blocks
__global__ __launch_bounds__(256) void k_fuse(const __half* __restrict__ hp, const __half* __restrict__ lp,
                                              const float* __restrict__ gbn, const float* __restrict__ bbn,
                                              const float* __restrict__ glow, const float* __restrict__ blow,
                                              const float* __restrict__ sh, const float* __restrict__ sl,
                                              __half* __restrict__ r) {
    int b, wblk;
    xcd_decode(blockIdx.x, 128, b, wblk);
    int idx = wblk*256 + threadIdx.x;        // 0..32767 h8-groups within batch
    int p = b*262144 + (idx << 3);
    int c = idx >> 11;                       // channel 0..15
    float muh = sh[b*2] * (1.f/262144.f);
    float varh = sh[b*2+1]*(1.f/262144.f) - muh*muh;
    float rsh = rsqrtf(varh + EPS);
    int gi = b*4 + (c>>3)*2;
    float mul = sl[gi] * (1.f/131072.f);
    float varl = sl[gi+1]*(1.f/131072.f) - mul*mul;
    float rsl = rsqrtf(varl + EPS);
    float ga = gbn[c]*rsh, bh = bbn[c] - muh*ga;
    float gl = glow[c]*rsl, bl = blow[c] - mul*gl;
    h8 hv = *(const h8*)(hp + (size_t)p);
    h8 lv = *(const h8*)(lp + (size_t)p);
    float2 h01 = __half22float2(hv.a), h23 = __half22float2(hv.b),
           h45 = __half22float2(hv.c), h67 = __half22float2(hv.d);
    float2 l01 = __half22float2(lv.a), l23 = __half22float2(lv.b),
           l45 = __half22float2(lv.c), l67 = __half22float2(lv.d);
    float o0 = mishf(h01.x*ga + bh + l01.x*gl + bl);
    float o1 = mishf(h01.y*ga + bh + l01.y*gl + bl);
    float o2 = mishf(h23.x*ga + bh + l23.x*gl + bl);
    float o3 = mishf(h23.y*ga + bh + l23.y*gl + bl);
    float o4 = mishf(h45.x*ga + bh + l45.x*gl + bl);
    float o5 = mishf(h45.y*ga + bh + l45.y*gl + bl);
    float o6 = mishf(h67.x*ga + bh + l67.x*gl + bl);
    float o7 = mishf(h67.y*ga + bh + l67.y*gl + bl);
    h8 ov;
    ov.a = __floats2half2_rn(o0,o1); ov.b = __floats2half2_rn(o2,o3);
    ov.c = __floats2half2_rn(o4,o5); ov.d = __floats2half2_rn(o6,o7);
    *(h8*)(r + (size_t)p) = ov;
}

// ---------------- K5: 3x3 conv 16->16 pad1; flat grid 3072, XCD-sharded ----------------
// per batch: 64 blocks = 2 co-half * 32 yblk (4 rows each)
__global__ __launch_bounds__(128) void k_ref6(const __half* __restrict__ rin,
                                              const float* __restrict__ WTr,
                                              const __half* __restrict__ zh,
                                              __half* __restrict__ outp,
                                              float* __restrict__ stat) {
    int b, w;
    xcd_decode(blockIdx.x, 64, b, w);
    int h  = w >> 5;
    int y0 = (w & 31) << 2;
    int tid = threadIdx.x;
    dconv4<1,16>(rin + (size_t)b*16*HW, WTr + h*1152, zh,
                 outp + (size_t)(b*16 + h*8)*HW, stat + b*4 + h*2, y0, tid);
}

// ---------------- K6: GN-apply + mish + 1x1 seg conv 16->1; 8 px/thread, fp16 ----------------
// grid 384 = 48 b * 8 blocks
__global__ __launch_bounds__(256) void k_seg(const __half* __restrict__ rp,
                                             const float* __restrict__ gref, const float* __restrict__ bref,
                                             const float* __restrict__ wseg, const float* __restrict__ sr,
                                             __half* __restrict__ seg) {
    int b, wblk;
    xcd_decode(blockIdx.x, 8, b, wblk);
    int off = ((wblk*256 + threadIdx.x) << 3);   // 0..16376 within batch plane
    const __half* pb = rp + (size_t)b*16*HW + off;
    float a0=0,a1=0,a2=0,a3=0,a4=0,a5=0,a6=0,a7=0;
    #pragma unroll
    for (int c = 0; c < 16; ++c) {
        int gi = b*4 + (c>>3)*2;
        float mu = sr[gi] * (1.f/131072.f);
        float var = sr[gi+1]*(1.f/131072.f) - mu*mu;
        float rs = rsqrtf(var + EPS);
        float ga = gref[c]*rs, bb = bref[c] - mu*ga;
        float wv = wseg[c];
        h8 v = *(const h8*)(pb + (size_t)c*HW);
        float2 v01 = __half22float2(v.a), v23 = __half22float2(v.b),
               v45 = __half22float2(v.c), v67 = __half22float2(v.d);
        a0 += wv*mishf(v01.x*ga + bb); a1 += wv*mishf(v01.y*ga + bb);
        a2 += wv*mishf(v23.x*ga + bb); a3 += wv*mishf(v23.y*ga + bb);
        a4 += wv*mishf(v45.x*ga + bb); a5 += wv*mishf(v45.y*ga + bb);
        a6 += wv*mishf(v67.x*ga + bb); a7 += wv*mishf(v67.y*ga + bb);
    }
    h8 ov;
    ov.a = __floats2half2_rn(a0,a1); ov.b = __floats2half2_rn(a2,a3);
    ov.c = __floats2half2_rn(a4,a5); ov.d = __floats2half2_rn(a6,a7);
    *(h8*)(seg + (size_t)b*HW + off) = ov;
}

// ---------------- K7: bilinear x4 upsample + sigmoid (seg fp16 -> out fp32) ----------------
__global__ __launch_bounds__(256) void k_up(const __half* __restrict__ seg, float* __restrict__ out) {
    int i4 = blockIdx.x * 256 + threadIdx.x;    // 3,145,728 total
    int b = i4 / (512*128);
    int rem = i4 - b*(512*128);
    int y = rem >> 7; int k = rem & 127;
    const __half* sp = seg + (size_t)b * HW;
    float fy = fminf(fmaxf(0.25f*y - 0.375f, 0.f), 127.f);
    int y0 = min((int)fy, 126);
    float wy = fy - (float)y0;
    const __half* r0 = sp + y0*WW;
    const __half* r1 = r0 + WW;
    float res[4];
    #pragma unroll
    for (int j = 0; j < 4; ++j) {
        int x = k*4 + j;
        float fx = fminf(fmaxf(0.25f*x - 0.375f, 0.f), 127.f);
        int x0 = min((int)fx, 126);
        float wx = fx - (float)x0;
        float v0 = __half2float(r0[x0])*(1.f-wx) + __half2float(r0[x0+1])*wx;
        float v1 = __half2float(r1[x0])*(1.f-wx) + __half2float(r1[x0+1])*wx;
        float v = v0*(1.f-wy) + v1*wy;
        res[j] = 1.f/(1.f + __expf(-v));
    }
    *(float4*)(out + (size_t)i4*4) = make_float4(res[0],res[1],res[2],res[3]);
}

extern "C" void kernel_launch(void* const* d_in, const int* in_sizes, int n_in,
                              void* d_out, int out_size, void* d_ws, size_t ws_size,
                              hipStream_t stream) {
    const float* low  = (const float*)d_in[0];
    const float* high = (const float*)d_in[1];
    const float* Wc0  = (const float*)d_in[2];
    const float* Wc1  = (const float*)d_in[3];
    const float* Wc2  = (const float*)d_in[4];
    const float* gbn  = (const float*)d_in[5];
    const float* bbn  = (const float*)d_in[6];
    const float* Wlow = (const float*)d_in[7];
    const float* glow = (const float*)d_in[8];
    const float* blow = (const float*)d_in[9];
    const float* Wref = (const float*)d_in[10];
    const float* gref = (const float*)d_in[11];
    const float* bref = (const float*)d_in[12];
    const float* Wseg = (const float*)d_in[13];

    float* ws = (float*)d_ws;
    // fp16 tensors live in fp32-sized slots (half the bytes used; layout kept simple)
    __half* A  = (__half*)ws;                        // in0, later r
    __half* Bb = (__half*)(ws + (size_t)SZ);         // high_pre, later ref_pre
    __half* C  = (__half*)(ws + 2*(size_t)SZ);       // low_pre
    __half* D  = (__half*)(ws + 3*(size_t)SZ);       // seg (48*16384 halfs)
    float* ST = ws + 3*(size_t)SZ + (size_t)48*HW;   // stats: 480 floats (zeroed each launch)
    float* ZB = ST + 480;                            // 64 zeroed floats: OOB-load redirect target
    float* WTb = ZB + 64;                            // 1152 floats
    float* WTr = WTb + 1152;                         // 2304 floats

    hipMemsetAsync(ST, 0, (480 + 64)*sizeof(float), stream);

    k_c0     <<<768,   256, 0, stream>>>(high, Wc0, Wc1, Wc2, Wref, WTb, WTr, A);
    k_branch6<<<3072,  128, 0, stream>>>(A, WTb, (const __half*)ZB, Bb, ST);
    k_low    <<<768,   256, 0, stream>>>(low, Wlow, C, ST + 96);
    k_fuse   <<<6144,  256, 0, stream>>>(Bb, C, gbn, bbn, glow, blow, ST, ST + 96, A);
    k_ref6   <<<3072,  128, 0, stream>>>(A, WTr, (const __half*)ZB, Bb, ST + 288);
    k_seg    <<<384,   256, 0, stream>>>(Bb, gref, bref, Wseg, ST + 288, D);
    k_up     <<<12288, 256, 0, stream>>>(D, (float*)d_out);
}

// Round 7
// 443.547 us; speedup vs baseline: 2.5718x; 2.5718x over previous
//
#include <hip/hip_runtime.h>
#include <hip/hip_fp16.h>
#include <math.h>

#define BATCH 48
#define HH 128
#define WW 128
#define HW (128*128)
#define SZ (48*16*HW)          // element count of a 16-ch feature map (fp32-slot sized regions)
#define EPS 1e-5f

// ---- fp16 vector helpers (storage fp16, compute fp32) ----
struct __align__(8)  h4 { __half2 a, b; };
struct __align__(16) h8 { __half2 a, b, c, d; };

__device__ __forceinline__ float4 h4f(h4 v) {
    float2 f0 = __half22float2(v.a), f1 = __half22float2(v.b);
    return make_float4(f0.x, f0.y, f1.x, f1.y);
}
__device__ __forceinline__ h4 f4h(float4 v) {
    h4 r; r.a = __floats2half2_rn(v.x, v.y); r.b = __floats2half2_rn(v.z, v.w); return r;
}

// mish(x) = x*tanh(softplus(x)) = x * t(t+2)/(t(t+2)+2), t = e^x  (exact identity)
__device__ __forceinline__ float mishf(float v) {
    float t = __expf(fminf(v, 20.f));
    float u = t * (t + 2.f);
    return v * (u / (u + 2.f));
}

// XCD-affinity decode: linear block L -> (xcd = L&7) owns batches b == xcd (mod 8).
__device__ __forceinline__ void xcd_decode(int L, int bpb, int& b, int& w) {
    int xcd = L & 7;
    int j   = L >> 3;
    b = xcd + 8 * (j / bpb);
    w = j - (j / bpb) * bpb;
}

// ---------------- K1: 1x1 conv 32->16 (high_fea -> in0 fp16) + weight transposes ----------------
// grid 768 = 48 b * 16 blocks; XCD-sharded by batch.  (round-5 proven form — do not touch:
// the chunk-prefetch variant spilled acc to scratch, VGPR=48, 1.26 GB scratch writes)
__global__ __launch_bounds__(256) void k_c0(const float* __restrict__ x,
                                            const float* __restrict__ W,
                                            const float* __restrict__ Wc1,
                                            const float* __restrict__ Wc2,
                                            const float* __restrict__ Wref,
                                            float* __restrict__ WTb,   // 1152 floats
                                            float* __restrict__ WTr,   // 2304 floats
                                            __half* __restrict__ out) {
    __shared__ float w[16*32];
    int tid = threadIdx.x;
    for (int i = tid; i < 512; i += 256) w[i] = W[i];
    if (blockIdx.x == 0) {
        for (int i = tid; i < 576; i += 256) {
            int co = i & 7; int t = i >> 3; int kyx = t % 9; int ci = t / 9;
            WTb[(ci*9 + kyx)*8 + co]       = Wc1[(co*8 + ci)*9 + kyx];
            WTb[576 + (ci*9 + kyx)*8 + co] = Wc2[(co*8 + ci)*9 + kyx];
        }
        for (int i = tid; i < 2304; i += 256) {
            int co = i & 7; int t = i >> 3; int kyx = t % 9; int cih = t / 9;  // 0..31
            int ci = cih & 15; int h = cih >> 4;
            WTr[((h*16 + ci)*9 + kyx)*8 + co] = Wref[((h*8 + co)*16 + ci)*9 + kyx];
        }
    }
    __syncthreads();
    int b, wblk;
    xcd_decode(blockIdx.x, 16, b, wblk);
    int off = ((wblk*256 + tid) << 2);       // 4 px per thread
    const float* xb = x + (size_t)b * 32 * HW + off;
    float acc[16][4];
    #pragma unroll
    for (int c = 0; c < 16; ++c) { acc[c][0]=acc[c][1]=acc[c][2]=acc[c][3]=0.f; }
    #pragma unroll 8
    for (int ci = 0; ci < 32; ++ci) {
        float4 xv = *(const float4*)(xb + (size_t)ci * HW);
        #pragma unroll
        for (int co = 0; co < 16; ++co) {
            float wv = w[co*32 + ci];
            acc[co][0] += wv*xv.x; acc[co][1] += wv*xv.y;
            acc[co][2] += wv*xv.z; acc[co][3] += wv*xv.w;
        }
    }
    __half* ob = out + (size_t)b * 16 * HW + off;
    #pragma unroll
    for (int co = 0; co < 16; ++co)
        *(h4*)(ob + (size_t)co * HW) = f4h(make_float4(acc[co][0],acc[co][1],acc[co][2],acc[co][3]));
}

// -------- direct-from-global 3x3 conv, fp16 in/out, 4 px/thread, one-group-ahead prefetch --------
// Tile 128 wide x 4 tall, 128 threads (tx 0..31, ty 0..3). Per (ci,ky): 3 h4 loads (window
// tx*4-4 .. +11) feeding 96 fp32 FMAs. Same rotating-buffer schedule as the proven round-5
// dconv8 (load group g+1 before computing group g); 2x the grid -> 24 waves/CU of work.
template<int D, int NCI>
__device__ __forceinline__ void dconv4(const __half* __restrict__ base,  // NCI ch planes
                                       const float* __restrict__ wb,     // NCI*72 [ci][kyx][co8]
                                       const __half* __restrict__ zh,    // >=16 zeroed halfs
                                       __half* __restrict__ obase,       // 8 ch planes
                                       float* __restrict__ statp,        // 2 floats
                                       int y0, int tid) {
    int tx = tid & 31, ty = tid >> 5;      // 32 x 4
    int y  = y0 + ty;
    int xg = tx*4 - 4;                     // leftmost loaded element (mult of 4)
    bool mx0 = (tx > 0);                   // h4 @ xg
    bool mx2 = (tx < 31);                  // h4 @ xg+8
    bool my[3];
    #pragma unroll
    for (int ky = 0; ky < 3; ++ky) my[ky] = ((unsigned)(y + D*(ky-1)) < 128u);

    float acc[8][4];
    #pragma unroll
    for (int c = 0; c < 8; ++c) { acc[c][0]=acc[c][1]=acc[c][2]=acc[c][3]=0.f; }

    h4 A0,A1,A2, B0,B1,B2, C0,C1,C2;

    auto LD = [&](const __half* cb, int ky, h4& d0, h4& d1, h4& d2) {
        const __half* rp = cb + (y + D*(ky-1))*WW;
        bool m = my[ky];
        d0 = *(const h4*)((m && mx0) ? rp     : zh);
        d1 = *(const h4*)( m         ? rp + 4 : zh);
        d2 = *(const h4*)((m && mx2) ? rp + 8 : zh);
    };
    auto FMAG = [&](const float* wp, h4 d0, h4 d1, h4 d2) {
        float4 f0 = h4f(d0), f1 = h4f(d1), f2 = h4f(d2);
        float u[12] = {f0.x,f0.y,f0.z,f0.w, f1.x,f1.y,f1.z,f1.w, f2.x,f2.y,f2.z,f2.w};
        #pragma unroll
        for (int kx = 0; kx < 3; ++kx) {
            const float* wq = wp + kx*8;
            float w0 = wq[0], w1 = wq[1], w2 = wq[2], w3 = wq[3];
            float w4 = wq[4], w5 = wq[5], w6 = wq[6], w7 = wq[7];
            #pragma unroll
            for (int j = 0; j < 4; ++j) {
                float xv = u[4 - D + D*kx + j];
                acc[0][j] += w0*xv; acc[1][j] += w1*xv;
                acc[2][j] += w2*xv; acc[3][j] += w3*xv;
                acc[4][j] += w4*xv; acc[5][j] += w5*xv;
                acc[6][j] += w6*xv; acc[7][j] += w7*xv;
            }
        }
    };

    const __half* cb = base + xg;
    const float* wp = wb;
    LD(cb, 0, A0,A1,A2);
    #pragma unroll 1
    for (int ci = 0; ci < NCI; ++ci) {
        LD(cb, 1, B0,B1,B2);
        FMAG(wp,      A0,A1,A2);
        LD(cb, 2, C0,C1,C2);
        FMAG(wp + 24, B0,B1,B2);
        if (ci + 1 < NCI) LD(cb + HW, 0, A0,A1,A2);
        FMAG(wp + 48, C0,C1,C2);
        cb += HW; wp += 72;
    }

    // ---- write (fp16) + GN partial stats (fp32) ----
    float s = 0.f, q = 0.f;
    __half* ob = obase + y*WW + tx*4;
    #pragma unroll
    for (int c = 0; c < 8; ++c) {
        *(h4*)(ob + (size_t)c*HW) = f4h(make_float4(acc[c][0],acc[c][1],acc[c][2],acc[c][3]));
        #pragma unroll
        for (int j = 0; j < 4; ++j) { s += acc[c][j]; q += acc[c][j]*acc[c][j]; }
    }
    #pragma unroll
    for (int o = 32; o > 0; o >>= 1) { s += __shfl_down(s,o); q += __shfl_down(q,o); }
    if ((tid & 63) == 0) { atomicAdd(&statp[0], s); atomicAdd(&statp[1], q); }
}

// ---------------- K2: dual-branch 3x3; flat grid 3072, XCD-sharded ----------------
// per batch: 64 blocks = 2 branch * 32 yblk (4 rows each)
__global__ __launch_bounds__(128) void k_branch7(const __half* __restrict__ in0,
                                                 const float* __restrict__ WTb,
                                                 const __half* __restrict__ zh,
                                                 __half* __restrict__ outp,
                                                 float* __restrict__ stat) {
    int b, w;
    xcd_decode(blockIdx.x, 64, b, w);
    int br = w >> 5;
    int y0 = (w & 31) << 2;
    int tid = threadIdx.x;
    if (br == 0) {
        dconv4<1,8>(in0 + (size_t)(b*16    )*HW, WTb,       zh,
                    outp + (size_t)(b*16    )*HW, stat + b*2, y0, tid);
    } else {
        dconv4<2,8>(in0 + (size_t)(b*16 + 8)*HW, WTb + 576, zh,
                    outp + (size_t)(b*16 + 8)*HW, stat + b*2, y0, tid);
    }
}

// ---------------- K3: 1x1 conv 24->16 (low, fp16 out) + GN(groups=2) stats ----------------
// (round-5 proven form)
__global__ __launch_bounds__(256) void k_low(const float* __restrict__ x,
                                             const float* __restrict__ W,
                                             __half* __restrict__ outp,
                                             float* __restrict__ stat) {
    __shared__ float w[16*24];
    int tid = threadIdx.x;
    for (int i = tid; i < 384; i += 256) w[i] = W[i];
    __syncthreads();
    int b, wblk;
    xcd_decode(blockIdx.x, 16, b, wblk);
    int off = ((wblk*256 + tid) << 2);
    const float* xb = x + (size_t)b * 24 * HW + off;
    float acc[16][4];
    #pragma unroll
    for (int c = 0; c < 16; ++c) { acc[c][0]=acc[c][1]=acc[c][2]=acc[c][3]=0.f; }
    #pragma unroll 8
    for (int ci = 0; ci < 24; ++ci) {
        float4 xv = *(const float4*)(xb + (size_t)ci * HW);
        #pragma unroll
        for (int co = 0; co < 16; ++co) {
            float wv = w[co*24 + ci];
            acc[co][0] += wv*xv.x; acc[co][1] += wv*xv.y;
            acc[co][2] += wv*xv.z; acc[co][3] += wv*xv.w;
        }
    }
    __half* ob = outp + (size_t)b * 16 * HW + off;
    float s0=0.f,q0=0.f,s1=0.f,q1=0.f;
    #pragma unroll
    for (int co = 0; co < 16; ++co) {
        *(h4*)(ob + (size_t)co * HW) = f4h(make_float4(acc[co][0],acc[co][1],acc[co][2],acc[co][3]));
        #pragma unroll
        for (int j = 0; j < 4; ++j) {
            if (co < 8) { s0 += acc[co][j]; q0 += acc[co][j]*acc[co][j]; }
            else        { s1 += acc[co][j]; q1 += acc[co][j]*acc[co][j]; }
        }
    }
    #pragma unroll
    for (int o = 32; o > 0; o >>= 1) {
        s0 += __shfl_down(s0,o); q0 += __shfl_down(q0,o);
        s1 += __shfl_down(s1,o); q1 += __shfl_down(q1,o);
    }
    if ((tid & 63) == 0) {
        atomicAdd(&stat[b*4+0], s0); atomicAdd(&stat[b*4+1], q0);
        atomicAdd(&stat[b*4+2], s1); atomicAdd(&stat[b*4+3], q1);
    }
}

// ---------------- K4: GN-apply (high & low) + add + mish; 8 px/thread, fp16 ----------------
// grid 6144 = 48 b * 128 blocks
__global__ __launch_bounds__(256) void k_fuse(const __half* __restrict__ hp, const __half* __restrict__ lp,
                                              const float* __restrict__ gbn, const float* __restrict__ bbn,
                                              const float* __restrict__ glow, const float* __restrict__ blow,
                                              const float* __restrict__ sh, const float* __restrict__ sl,
                                              __half* __restrict__ r) {
    int b, wblk;
    xcd_decode(blockIdx.x, 128, b, wblk);
    int idx = wblk*256 + threadIdx.x;        // 0..32767 h8-groups within batch
    int p = b*262144 + (idx << 3);
    int c = idx >> 11;                       // channel 0..15
    float muh = sh[b*2] * (1.f/262144.f);
    float varh = sh[b*2+1]*(1.f/262144.f) - muh*muh;
    float rsh = rsqrtf(varh + EPS);
    int gi = b*4 + (c>>3)*2;
    float mul = sl[gi] * (1.f/131072.f);
    float varl = sl[gi+1]*(1.f/131072.f) - mul*mul;
    float rsl = rsqrtf(varl + EPS);
    float ga = gbn[c]*rsh, bh = bbn[c] - muh*ga;
    float gl = glow[c]*rsl, bl = blow[c] - mul*gl;
    h8 hv = *(const h8*)(hp + (size_t)p);
    h8 lv = *(const h8*)(lp + (size_t)p);
    float2 h01 = __half22float2(hv.a), h23 = __half22float2(hv.b),
           h45 = __half22float2(hv.c), h67 = __half22float2(hv.d);
    float2 l01 = __half22float2(lv.a), l23 = __half22float2(lv.b),
           l45 = __half22float2(lv.c), l67 = __half22float2(lv.d);
    float o0 = mishf(h01.x*ga + bh + l01.x*gl + bl);
    float o1 = mishf(h01.y*ga + bh + l01.y*gl + bl);
    float o2 = mishf(h23.x*ga + bh + l23.x*gl + bl);
    float o3 = mishf(h23.y*ga + bh + l23.y*gl + bl);
    float o4 = mishf(h45.x*ga + bh + l45.x*gl + bl);
    float o5 = mishf(h45.y*ga + bh + l45.y*gl + bl);
    float o6 = mishf(h67.x*ga + bh + l67.x*gl + bl);
    float o7 = mishf(h67.y*ga + bh + l67.y*gl + bl);
    h8 ov;
    ov.a = __floats2half2_rn(o0,o1); ov.b = __floats2half2_rn(o2,o3);
    ov.c = __floats2half2_rn(o4,o5); ov.d = __floats2half2_rn(o6,o7);
    *(h8*)(r + (size_t)p) = ov;
}

// ---------------- K5: 3x3 conv 16->16 pad1; flat grid 3072, XCD-sharded ----------------
// per batch: 64 blocks = 2 co-half * 32 yblk (4 rows each)
__global__ __launch_bounds__(128) void k_ref7(const __half* __restrict__ rin,
                                              const float* __restrict__ WTr,
                                              const __half* __restrict__ zh,
                                              __half* __restrict__ outp,
                                              float* __restrict__ stat) {
    int b, w;
    xcd_decode(blockIdx.x, 64, b, w);
    int h  = w >> 5;
    int y0 = (w & 31) << 2;
    int tid = threadIdx.x;
    dconv4<1,16>(rin + (size_t)b*16*HW, WTr + h*1152, zh,
                 outp + (size_t)(b*16 + h*8)*HW, stat + b*4 + h*2, y0, tid);
}

// ---------------- K6: GN-apply + mish + 1x1 seg conv 16->1; 8 px/thread, fp16 ----------------
// grid 384 = 48 b * 8 blocks
__global__ __launch_bounds__(256) void k_seg(const __half* __restrict__ rp,
                                             const float* __restrict__ gref, const float* __restrict__ bref,
                                             const float* __restrict__ wseg, const float* __restrict__ sr,
                                             __half* __restrict__ seg) {
    int b, wblk;
    xcd_decode(blockIdx.x, 8, b, wblk);
    int off = ((wblk*256 + threadIdx.x) << 3);   // 0..16376 within batch plane
    const __half* pb = rp + (size_t)b*16*HW + off;
    float a0=0,a1=0,a2=0,a3=0,a4=0,a5=0,a6=0,a7=0;
    #pragma unroll
    for (int c = 0; c < 16; ++c) {
        int gi = b*4 + (c>>3)*2;
        float mu = sr[gi] * (1.f/131072.f);
        float var = sr[gi+1]*(1.f/131072.f) - mu*mu;
        float rs = rsqrtf(var + EPS);
        float ga = gref[c]*rs, bb = bref[c] - mu*ga;
        float wv = wseg[c];
        h8 v = *(const h8*)(pb + (size_t)c*HW);
        float2 v01 = __half22float2(v.a), v23 = __half22float2(v.b),
               v45 = __half22float2(v.c), v67 = __half22float2(v.d);
        a0 += wv*mishf(v01.x*ga + bb); a1 += wv*mishf(v01.y*ga + bb);
        a2 += wv*mishf(v23.x*ga + bb); a3 += wv*mishf(v23.y*ga + bb);
        a4 += wv*mishf(v45.x*ga + bb); a5 += wv*mishf(v45.y*ga + bb);
        a6 += wv*mishf(v67.x*ga + bb); a7 += wv*mishf(v67.y*ga + bb);
    }
    h8 ov;
    ov.a = __floats2half2_rn(a0,a1); ov.b = __floats2half2_rn(a2,a3);
    ov.c = __floats2half2_rn(a4,a5); ov.d = __floats2half2_rn(a6,a7);
    *(h8*)(seg + (size_t)b*HW + off) = ov;
}

// ---------------- K7: bilinear x4 upsample + sigmoid (seg fp16 -> out fp32) ----------------
__global__ __launch_bounds__(256) void k_up(const __half* __restrict__ seg, float* __restrict__ out) {
    int i4 = blockIdx.x * 256 + threadIdx.x;    // 3,145,728 total
    int b = i4 / (512*128);
    int rem = i4 - b*(512*128);
    int y = rem >> 7; int k = rem & 127;
    const __half* sp = seg + (size_t)b * HW;
    float fy = fminf(fmaxf(0.25f*y - 0.375f, 0.f), 127.f);
    int y0 = min((int)fy, 126);
    float wy = fy - (float)y0;
    const __half* r0 = sp + y0*WW;
    const __half* r1 = r0 + WW;
    float res[4];
    #pragma unroll
    for (int j = 0; j < 4; ++j) {
        int x = k*4 + j;
        float fx = fminf(fmaxf(0.25f*x - 0.375f, 0.f), 127.f);
        int x0 = min((int)fx, 126);
        float wx = fx - (float)x0;
        float v0 = __half2float(r0[x0])*(1.f-wx) + __half2float(r0[x0+1])*wx;
        float v1 = __half2float(r1[x0])*(1.f-wx) + __half2float(r1[x0+1])*wx;
        float v = v0*(1.f-wy) + v1*wy;
        res[j] = 1.f/(1.f + __expf(-v));
    }
    *(float4*)(out + (size_t)i4*4) = make_float4(res[0],res[1],res[2],res[3]);
}

extern "C" void kernel_launch(void* const* d_in, const int* in_sizes, int n_in,
                              void* d_out, int out_size, void* d_ws, size_t ws_size,
                              hipStream_t stream) {
    const float* low  = (const float*)d_in[0];
    const float* high = (const float*)d_in[1];
    const float* Wc0  = (const float*)d_in[2];
    const float* Wc1  = (const float*)d_in[3];
    const float* Wc2  = (const float*)d_in[4];
    const float* gbn  = (const float*)d_in[5];
    const float* bbn  = (const float*)d_in[6];
    const float* Wlow = (const float*)d_in[7];
    const float* glow = (const float*)d_in[8];
    const float* blow = (const float*)d_in[9];
    const float* Wref = (const float*)d_in[10];
    const float* gref = (const float*)d_in[11];
    const float* bref = (const float*)d_in[12];
    const float* Wseg = (const float*)d_in[13];

    float* ws = (float*)d_ws;
    // fp16 tensors live in fp32-sized slots (half the bytes used; layout kept simple)
    __half* A  = (__half*)ws;                        // in0, later r
    __half* Bb = (__half*)(ws + (size_t)SZ);         // high_pre, later ref_pre
    __half* C  = (__half*)(ws + 2*(size_t)SZ);       // low_pre
    __half* D  = (__half*)(ws + 3*(size_t)SZ);       // seg (48*16384 halfs)
    float* ST = ws + 3*(size_t)SZ + (size_t)48*HW;   // stats: 480 floats (zeroed each launch)
    float* ZB = ST + 480;                            // 64 zeroed floats: OOB-load redirect target
    float* WTb = ZB + 64;                            // 1152 floats
    float* WTr = WTb + 1152;                         // 2304 floats

    hipMemsetAsync(ST, 0, (480 + 64)*sizeof(float), stream);

    k_c0     <<<768,   256, 0, stream>>>(high, Wc0, Wc1, Wc2, Wref, WTb, WTr, A);
    k_branch7<<<3072,  128, 0, stream>>>(A, WTb, (const __half*)ZB, Bb, ST);
    k_low    <<<768,   256, 0, stream>>>(low, Wlow, C, ST + 96);
    k_fuse   <<<6144,  256, 0, stream>>>(Bb, C, gbn, bbn, glow, blow, ST, ST + 96, A);
    k_ref7   <<<3072,  128, 0, stream>>>(A, WTr, (const __half*)ZB, Bb, ST + 288);
    k_seg    <<<384,   256, 0, stream>>>(Bb, gref, bref, Wseg, ST + 288, D);
    k_up     <<<12288, 256, 0, stream>>>(D, (float*)d_out);
}

// Round 8
// 391.324 us; speedup vs baseline: 2.9151x; 1.1335x over previous
//
#include <hip/hip_runtime.h>
#include <hip/hip_fp16.h>
#include <math.h>

#define BATCH 48
#define HH 128
#define WW 128
#define HW (128*128)
#define PHW (132*128)          // padded channel stride (2 zero rows top + bottom)
#define PCH (16*PHW)           // padded 16-ch batch stride
#define SZ (48*16*HW)          // fp32-slot element count of a 16-ch feature map
#define EPS 1e-5f

// ---- fp16 vector helpers (storage fp16, compute fp32) ----
struct __align__(8)  h4 { __half2 a, b; };
struct __align__(16) h8 { __half2 a, b, c, d; };

__device__ __forceinline__ float4 h4f(h4 v) {
    float2 f0 = __half22float2(v.a), f1 = __half22float2(v.b);
    return make_float4(f0.x, f0.y, f1.x, f1.y);
}
__device__ __forceinline__ h4 f4h(float4 v) {
    h4 r; r.a = __floats2half2_rn(v.x, v.y); r.b = __floats2half2_rn(v.z, v.w); return r;
}

// mish(x) = x*tanh(softplus(x)) = x * t(t+2)/(t(t+2)+2), t = e^x  (exact identity)
__device__ __forceinline__ float mishf(float v) {
    float t = __expf(fminf(v, 20.f));
    float u = t * (t + 2.f);
    return v * (u / (u + 2.f));
}

// XCD-affinity decode: linear block L -> (xcd = L&7) owns batches b == xcd (mod 8).
__device__ __forceinline__ void xcd_decode(int L, int bpb, int& b, int& w) {
    int xcd = L & 7;
    int j   = L >> 3;
    b = xcd + 8 * (j / bpb);
    w = j - (j / bpb) * bpb;
}

// ---------------- K1: 1x1 conv 32->16 (high_fea -> padded in0 fp16) + weight transposes ----------------
// grid 768 = 48 b * 16 blocks; XCD-sharded. Round-5 proven inner form (chunk-prefetch spilled).
// Also zeroes the 4 pad rows per channel (persist through A-slot reuse as r).
__global__ __launch_bounds__(256) void k_c0(const float* __restrict__ x,
                                            const float* __restrict__ W,
                                            const float* __restrict__ Wc1,
                                            const float* __restrict__ Wc2,
                                            const float* __restrict__ Wref,
                                            float* __restrict__ WTb,   // 1152 floats
                                            float* __restrict__ WTr,   // 2304 floats
                                            __half* __restrict__ out) {
    __shared__ float w[16*32];
    int tid = threadIdx.x;
    for (int i = tid; i < 512; i += 256) w[i] = W[i];
    if (blockIdx.x == 0) {
        for (int i = tid; i < 576; i += 256) {
            int co = i & 7; int t = i >> 3; int kyx = t % 9; int ci = t / 9;
            WTb[(ci*9 + kyx)*8 + co]       = Wc1[(co*8 + ci)*9 + kyx];
            WTb[576 + (ci*9 + kyx)*8 + co] = Wc2[(co*8 + ci)*9 + kyx];
        }
        for (int i = tid; i < 2304; i += 256) {
            int co = i & 7; int t = i >> 3; int kyx = t % 9; int cih = t / 9;  // 0..31
            int ci = cih & 15; int h = cih >> 4;
            WTr[((h*16 + ci)*9 + kyx)*8 + co] = Wref[((h*8 + co)*16 + ci)*9 + kyx];
        }
    }
    __syncthreads();
    int b, wblk;
    xcd_decode(blockIdx.x, 16, b, wblk);

    // zero pad rows 0,1,130,131 of all 16 channels for this batch (done by wblk==0)
    if (wblk == 0) {
        h4 z; z.a = __floats2half2_rn(0.f, 0.f); z.b = z.a;
        for (int i = tid; i < 2048; i += 256) {
            int ch = i >> 7;                 // 0..15
            int r4 = (i >> 5) & 3;           // 0..3
            int cc = (i & 31) << 2;          // 0..124
            int row = (r4 < 2) ? r4 : (r4 + 128);   // 0,1,130,131
            *(h4*)(out + (size_t)b*PCH + (size_t)ch*PHW + row*128 + cc) = z;
        }
    }

    int off = ((wblk*256 + tid) << 2);       // 4 px per thread
    const float* xb = x + (size_t)b * 32 * HW + off;
    float acc[16][4];
    #pragma unroll
    for (int c = 0; c < 16; ++c) { acc[c][0]=acc[c][1]=acc[c][2]=acc[c][3]=0.f; }
    #pragma unroll 8
    for (int ci = 0; ci < 32; ++ci) {
        float4 xv = *(const float4*)(xb + (size_t)ci * HW);
        #pragma unroll
        for (int co = 0; co < 16; ++co) {
            float wv = w[co*32 + ci];
            acc[co][0] += wv*xv.x; acc[co][1] += wv*xv.y;
            acc[co][2] += wv*xv.z; acc[co][3] += wv*xv.w;
        }
    }
    __half* ob = out + (size_t)b * PCH + 256 + off;   // +256 = 2 pad rows
    #pragma unroll
    for (int co = 0; co < 16; ++co)
        *(h4*)(ob + (size_t)co * PHW) = f4h(make_float4(acc[co][0],acc[co][1],acc[co][2],acc[co][3]));
}

// -------- direct-from-global 3x3 conv on PADDED fp16 input, 8 px/thread, round-5 pipeline --------
// Tile 128 wide x 8 tall, 128 threads. No y-masks (pad rows are zero); x-edge via zh redirect.
template<int D, int NCI>
__device__ __forceinline__ void dconv8p(const __half* __restrict__ base,  // padded, +2-row offset applied
                                        const float* __restrict__ wb,     // NCI*72 [ci][kyx][co8]
                                        const __half* __restrict__ zh,    // >=8 zeroed halfs
                                        __half* __restrict__ obase,       // 8 ch planes (unpadded)
                                        float* __restrict__ statp,        // 2 floats
                                        int y0, int tid) {
    int tx = tid & 15, ty = tid >> 4;      // 16 x 8
    int y  = y0 + ty;
    int xg = tx*8 - 4;                     // leftmost loaded element (mult of 4)
    bool mx0 = (tx > 0);                   // h4 @ xg
    bool mx3 = (tx < 15);                  // h4 @ xg+12

    float acc[8][8];
    #pragma unroll
    for (int c = 0; c < 8; ++c)
        #pragma unroll
        for (int j = 0; j < 8; ++j) acc[c][j] = 0.f;

    h4 A0,A1,A2,A3, B0,B1,B2,B3, C0,C1,C2,C3;

    auto LD = [&](const __half* cb, int ky, h4& d0, h4& d1, h4& d2, h4& d3) {
        const __half* rp = cb + (y + D*(ky-1))*WW;
        d0 = *(const h4*)(mx0 ? rp      : zh);
        d1 = *(const h4*)(rp + 4);
        d2 = *(const h4*)(rp + 8);
        d3 = *(const h4*)(mx3 ? rp + 12 : zh);
    };
    auto FMAG = [&](const float* wp, h4 d0, h4 d1, h4 d2, h4 d3) {
        float4 f0 = h4f(d0), f1 = h4f(d1), f2 = h4f(d2), f3 = h4f(d3);
        float u[16] = {f0.x,f0.y,f0.z,f0.w, f1.x,f1.y,f1.z,f1.w,
                       f2.x,f2.y,f2.z,f2.w, f3.x,f3.y,f3.z,f3.w};
        #pragma unroll
        for (int kx = 0; kx < 3; ++kx) {
            const float* wq = wp + kx*8;
            float w0 = wq[0], w1 = wq[1], w2 = wq[2], w3 = wq[3];
            float w4 = wq[4], w5 = wq[5], w6 = wq[6], w7 = wq[7];
            #pragma unroll
            for (int j = 0; j < 8; ++j) {
                float xv = u[4 - D + D*kx + j];
                acc[0][j] += w0*xv; acc[1][j] += w1*xv;
                acc[2][j] += w2*xv; acc[3][j] += w3*xv;
                acc[4][j] += w4*xv; acc[5][j] += w5*xv;
                acc[6][j] += w6*xv; acc[7][j] += w7*xv;
            }
        }
    };

    const __half* cb = base + xg;
    const float* wp = wb;
    LD(cb, 0, A0,A1,A2,A3);
    #pragma unroll 1
    for (int ci = 0; ci < NCI; ++ci) {
        LD(cb, 1, B0,B1,B2,B3);
        FMAG(wp,      A0,A1,A2,A3);
        LD(cb, 2, C0,C1,C2,C3);
        FMAG(wp + 24, B0,B1,B2,B3);
        if (ci + 1 < NCI) LD(cb + PHW, 0, A0,A1,A2,A3);
        FMAG(wp + 48, C0,C1,C2,C3);
        cb += PHW; wp += 72;
    }

    // ---- write (fp16, unpadded) + GN partial stats (fp32) ----
    float s = 0.f, q = 0.f;
    __half* ob = obase + y*WW + tx*8;
    #pragma unroll
    for (int c = 0; c < 8; ++c) {
        h8 o;
        o.a = __floats2half2_rn(acc[c][0], acc[c][1]);
        o.b = __floats2half2_rn(acc[c][2], acc[c][3]);
        o.c = __floats2half2_rn(acc[c][4], acc[c][5]);
        o.d = __floats2half2_rn(acc[c][6], acc[c][7]);
        *(h8*)(ob + (size_t)c*HW) = o;
        #pragma unroll
        for (int j = 0; j < 8; ++j) { s += acc[c][j]; q += acc[c][j]*acc[c][j]; }
    }
    #pragma unroll
    for (int o = 32; o > 0; o >>= 1) { s += __shfl_down(s,o); q += __shfl_down(q,o); }
    if ((tid & 63) == 0) { atomicAdd(&statp[0], s); atomicAdd(&statp[1], q); }
}

// ---------------- K2: MERGED dual-branch 3x3 conv + low 1x1 conv; grid 3072 x 128 ----------------
// Per batch: 64 sub-blocks, parity-interleaved: even -> branch conv (latency-bound),
// odd -> low 1x1 (BW-bound). Complementary types co-resident per CU fill each other's bubbles.
__global__ __launch_bounds__(128) void k_bl(const __half* __restrict__ in0p,   // padded
                                            const float* __restrict__ WTb,
                                            const __half* __restrict__ zh,
                                            __half* __restrict__ hout,         // high_pre (unpadded)
                                            float* __restrict__ stat_br,       // 2/batch
                                            const float* __restrict__ xlow,
                                            const float* __restrict__ Wlow,
                                            __half* __restrict__ lout,         // low_pre (unpadded)
                                            float* __restrict__ stat_low) {    // 4/batch
    __shared__ float wsm[16*24];
    int tid = threadIdx.x;
    int b, w;
    xcd_decode(blockIdx.x, 64, b, w);
    int type = w & 1;
    int sub  = w >> 1;                      // 0..31

    if (type == 0) {
        // ---- branch conv: sub = br*16 + yblk ----
        int br = sub >> 4;
        int y0 = (sub & 15) << 3;
        if (br == 0) {
            dconv8p<1,8>(in0p + (size_t)b*PCH + 256,            WTb,       zh,
                         hout + (size_t)(b*16    )*HW, stat_br + b*2, y0, tid);
        } else {
            dconv8p<2,8>(in0p + (size_t)b*PCH + 8*(size_t)PHW + 256, WTb + 576, zh,
                         hout + (size_t)(b*16 + 8)*HW, stat_br + b*2, y0, tid);
        }
    } else {
        // ---- low 1x1 conv 24->16 + GN(groups=2) stats (round-5 inner form, 128 threads) ----
        for (int i = tid; i < 384; i += 128) wsm[i] = Wlow[i];
        __syncthreads();
        int off = ((sub*128 + tid) << 2);   // 512 px per sub-block
        const float* xb = xlow + (size_t)b * 24 * HW + off;
        float acc[16][4];
        #pragma unroll
        for (int c = 0; c < 16; ++c) { acc[c][0]=acc[c][1]=acc[c][2]=acc[c][3]=0.f; }
        #pragma unroll 8
        for (int ci = 0; ci < 24; ++ci) {
            float4 xv = *(const float4*)(xb + (size_t)ci * HW);
            #pragma unroll
            for (int co = 0; co < 16; ++co) {
                float wv = wsm[co*24 + ci];
                acc[co][0] += wv*xv.x; acc[co][1] += wv*xv.y;
                acc[co][2] += wv*xv.z; acc[co][3] += wv*xv.w;
            }
        }
        __half* ob = lout + (size_t)b * 16 * HW + off;
        float s0=0.f,q0=0.f,s1=0.f,q1=0.f;
        #pragma unroll
        for (int co = 0; co < 16; ++co) {
            *(h4*)(ob + (size_t)co * HW) = f4h(make_float4(acc[co][0],acc[co][1],acc[co][2],acc[co][3]));
            #pragma unroll
            for (int j = 0; j < 4; ++j) {
                if (co < 8) { s0 += acc[co][j]; q0 += acc[co][j]*acc[co][j]; }
                else        { s1 += acc[co][j]; q1 += acc[co][j]*acc[co][j]; }
            }
        }
        #pragma unroll
        for (int o = 32; o > 0; o >>= 1) {
            s0 += __shfl_down(s0,o); q0 += __shfl_down(q0,o);
            s1 += __shfl_down(s1,o); q1 += __shfl_down(q1,o);
        }
        if ((tid & 63) == 0) {
            atomicAdd(&stat_low[b*4+0], s0); atomicAdd(&stat_low[b*4+1], q0);
            atomicAdd(&stat_low[b*4+2], s1); atomicAdd(&stat_low[b*4+3], q1);
        }
    }
}

// ---------------- K4: GN-apply (high & low) + add + mish -> padded r; 8 px/thread ----------------
// grid 6144 = 48 b * 128 blocks
__global__ __launch_bounds__(256) void k_fuse(const __half* __restrict__ hp, const __half* __restrict__ lp,
                                              const float* __restrict__ gbn, const float* __restrict__ bbn,
                                              const float* __restrict__ glow, const float* __restrict__ blow,
                                              const float* __restrict__ sh, const float* __restrict__ sl,
                                              __half* __restrict__ r) {      // padded
    int b, wblk;
    xcd_decode(blockIdx.x, 128, b, wblk);
    int idx = wblk*256 + threadIdx.x;        // 0..32767 h8-groups within batch
    int p = b*262144 + (idx << 3);
    int c = idx >> 11;                       // channel 0..15
    int pxin = (idx << 3) & 16383;           // in-channel pixel offset
    float muh = sh[b*2] * (1.f/262144.f);
    float varh = sh[b*2+1]*(1.f/262144.f) - muh*muh;
    float rsh = rsqrtf(varh + EPS);
    int gi = b*4 + (c>>3)*2;
    float mul = sl[gi] * (1.f/131072.f);
    float varl = sl[gi+1]*(1.f/131072.f) - mul*mul;
    float rsl = rsqrtf(varl + EPS);
    float ga = gbn[c]*rsh, bh = bbn[c] - muh*ga;
    float gl = glow[c]*rsl, bl = blow[c] - mul*gl;
    h8 hv = *(const h8*)(hp + (size_t)p);
    h8 lv = *(const h8*)(lp + (size_t)p);
    float2 h01 = __half22float2(hv.a), h23 = __half22float2(hv.b),
           h45 = __half22float2(hv.c), h67 = __half22float2(hv.d);
    float2 l01 = __half22float2(lv.a), l23 = __half22float2(lv.b),
           l45 = __half22float2(lv.c), l67 = __half22float2(lv.d);
    float o0 = mishf(h01.x*ga + bh + l01.x*gl + bl);
    float o1 = mishf(h01.y*ga + bh + l01.y*gl + bl);
    float o2 = mishf(h23.x*ga + bh + l23.x*gl + bl);
    float o3 = mishf(h23.y*ga + bh + l23.y*gl + bl);
    float o4 = mishf(h45.x*ga + bh + l45.x*gl + bl);
    float o5 = mishf(h45.y*ga + bh + l45.y*gl + bl);
    float o6 = mishf(h67.x*ga + bh + l67.x*gl + bl);
    float o7 = mishf(h67.y*ga + bh + l67.y*gl + bl);
    h8 ov;
    ov.a = __floats2half2_rn(o0,o1); ov.b = __floats2half2_rn(o2,o3);
    ov.c = __floats2half2_rn(o4,o5); ov.d = __floats2half2_rn(o6,o7);
    *(h8*)(r + (size_t)b*PCH + (size_t)c*PHW + 256 + pxin) = ov;
}

// ---------------- K5: 3x3 conv 16->16 pad1 on padded r; grid 1536 x 128, XCD-sharded ----------------
// per batch: 32 blocks = 2 co-half * 16 yblk (8 rows each) — round-5 proven geometry
__global__ __launch_bounds__(128) void k_refp(const __half* __restrict__ rin,  // padded
                                              const float* __restrict__ WTr,
                                              const __half* __restrict__ zh,
                                              __half* __restrict__ outp,
                                              float* __restrict__ stat) {
    int b, w;
    xcd_decode(blockIdx.x, 32, b, w);
    int h  = w >> 4;
    int y0 = (w & 15) << 3;
    int tid = threadIdx.x;
    dconv8p<1,16>(rin + (size_t)b*PCH + 256, WTr + h*1152, zh,
                  outp + (size_t)(b*16 + h*8)*HW, stat + b*4 + h*2, y0, tid);
}

// ---------------- K6: GN-apply + mish + 1x1 seg conv 16->1; 8 px/thread, fp16 ----------------
// grid 384 = 48 b * 8 blocks
__global__ __launch_bounds__(256) void k_seg(const __half* __restrict__ rp,
                                             const float* __restrict__ gref, const float* __restrict__ bref,
                                             const float* __restrict__ wseg, const float* __restrict__ sr,
                                             __half* __restrict__ seg) {
    int b, wblk;
    xcd_decode(blockIdx.x, 8, b, wblk);
    int off = ((wblk*256 + threadIdx.x) << 3);   // 0..16376 within batch plane
    const __half* pb = rp + (size_t)b*16*HW + off;
    float a0=0,a1=0,a2=0,a3=0,a4=0,a5=0,a6=0,a7=0;
    #pragma unroll
    for (int c = 0; c < 16; ++c) {
        int gi = b*4 + (c>>3)*2;
        float mu = sr[gi] * (1.f/131072.f);
        float var = sr[gi+1]*(1.f/131072.f) - mu*mu;
        float rs = rsqrtf(var + EPS);
        float ga = gref[c]*rs, bb = bref[c] - mu*ga;
        float wv = wseg[c];
        h8 v = *(const h8*)(pb + (size_t)c*HW);
        float2 v01 = __half22float2(v.a), v23 = __half22float2(v.b),
               v45 = __half22float2(v.c), v67 = __half22float2(v.d);
        a0 += wv*mishf(v01.x*ga + bb); a1 += wv*mishf(v01.y*ga + bb);
        a2 += wv*mishf(v23.x*ga + bb); a3 += wv*mishf(v23.y*ga + bb);
        a4 += wv*mishf(v45.x*ga + bb); a5 += wv*mishf(v45.y*ga + bb);
        a6 += wv*mishf(v67.x*ga + bb); a7 += wv*mishf(v67.y*ga + bb);
    }
    h8 ov;
    ov.a = __floats2half2_rn(a0,a1); ov.b = __floats2half2_rn(a2,a3);
    ov.c = __floats2half2_rn(a4,a5); ov.d = __floats2half2_rn(a6,a7);
    *(h8*)(seg + (size_t)b*HW + off) = ov;
}

// ---------------- K7: bilinear x4 upsample + sigmoid (seg fp16 -> out fp32) ----------------
__global__ __launch_bounds__(256) void k_up(const __half* __restrict__ seg, float* __restrict__ out) {
    int i4 = blockIdx.x * 256 + threadIdx.x;    // 3,145,728 total
    int b = i4 / (512*128);
    int rem = i4 - b*(512*128);
    int y = rem >> 7; int k = rem & 127;
    const __half* sp = seg + (size_t)b * HW;
    float fy = fminf(fmaxf(0.25f*y - 0.375f, 0.f), 127.f);
    int y0 = min((int)fy, 126);
    float wy = fy - (float)y0;
    const __half* r0 = sp + y0*WW;
    const __half* r1 = r0 + WW;
    float res[4];
    #pragma unroll
    for (int j = 0; j < 4; ++j) {
        int x = k*4 + j;
        float fx = fminf(fmaxf(0.25f*x - 0.375f, 0.f), 127.f);
        int x0 = min((int)fx, 126);
        float wx = fx - (float)x0;
        float v0 = __half2float(r0[x0])*(1.f-wx) + __half2float(r0[x0+1])*wx;
        float v1 = __half2float(r1[x0])*(1.f-wx) + __half2float(r1[x0+1])*wx;
        float v = v0*(1.f-wy) + v1*wy;
        res[j] = 1.f/(1.f + __expf(-v));
    }
    *(float4*)(out + (size_t)i4*4) = make_float4(res[0],res[1],res[2],res[3]);
}

extern "C" void kernel_launch(void* const* d_in, const int* in_sizes, int n_in,
                              void* d_out, int out_size, void* d_ws, size_t ws_size,
                              hipStream_t stream) {
    const float* low  = (const float*)d_in[0];
    const float* high = (const float*)d_in[1];
    const float* Wc0  = (const float*)d_in[2];
    const float* Wc1  = (const float*)d_in[3];
    const float* Wc2  = (const float*)d_in[4];
    const float* gbn  = (const float*)d_in[5];
    const float* bbn  = (const float*)d_in[6];
    const float* Wlow = (const float*)d_in[7];
    const float* glow = (const float*)d_in[8];
    const float* blow = (const float*)d_in[9];
    const float* Wref = (const float*)d_in[10];
    const float* gref = (const float*)d_in[11];
    const float* bref = (const float*)d_in[12];
    const float* Wseg = (const float*)d_in[13];

    float* ws = (float*)d_ws;
    // A: PADDED fp16 tensor (in0, later r): 48*16*132*128 halfs = 26 MB, fits the 50 MB fp32 slot
    __half* A  = (__half*)ws;
    __half* Bb = (__half*)(ws + (size_t)SZ);         // high_pre, later ref_pre (unpadded)
    __half* C  = (__half*)(ws + 2*(size_t)SZ);       // low_pre (unpadded)
    __half* D  = (__half*)(ws + 3*(size_t)SZ);       // seg (48*16384 halfs)
    float* ST = ws + 3*(size_t)SZ + (size_t)48*HW;   // stats: 480 floats (zeroed each launch)
    float* ZB = ST + 480;                            // 64 zeroed floats: x-OOB redirect target
    float* WTb = ZB + 64;                            // 1152 floats
    float* WTr = WTb + 1152;                         // 2304 floats

    hipMemsetAsync(ST, 0, (480 + 64)*sizeof(float), stream);

    k_c0  <<<768,   256, 0, stream>>>(high, Wc0, Wc1, Wc2, Wref, WTb, WTr, A);
    k_bl  <<<3072,  128, 0, stream>>>(A, WTb, (const __half*)ZB, Bb, ST,
                                      low, Wlow, C, ST + 96);
    k_fuse<<<6144,  256, 0, stream>>>(Bb, C, gbn, bbn, glow, blow, ST, ST + 96, A);
    k_refp<<<1536,  128, 0, stream>>>(A, WTr, (const __half*)ZB, Bb, ST + 288);
    k_seg <<<384,   256, 0, stream>>>(Bb, gref, bref, Wseg, ST + 288, D);
    k_up  <<<12288, 256, 0, stream>>>(D, (float*)d_out);
}

// Round 9
// 383.551 us; speedup vs baseline: 2.9741x; 1.0203x over previous
//
#include <hip/hip_runtime.h>
#include <hip/hip_fp16.h>
#include <math.h>

#define BATCH 48
#define HH 128
#define WW 128
#define HW (128*128)
#define PHW (132*128)          // padded channel stride (2 zero rows top + bottom)
#define PCH (16*PHW)           // padded 16-ch batch stride
#define SZ (48*16*HW)          // fp32-slot element count of a 16-ch feature map
#define EPS 1e-5f

// ---- fp16 vector helpers (storage fp16, compute fp32) ----
struct __align__(8)  h4 { __half2 a, b; };
struct __align__(16) h8 { __half2 a, b, c, d; };

__device__ __forceinline__ float4 h4f(h4 v) {
    float2 f0 = __half22float2(v.a), f1 = __half22float2(v.b);
    return make_float4(f0.x, f0.y, f1.x, f1.y);
}
__device__ __forceinline__ h4 f4h(float4 v) {
    h4 r; r.a = __floats2half2_rn(v.x, v.y); r.b = __floats2half2_rn(v.z, v.w); return r;
}

// mish(x) = x*tanh(softplus(x)) = x * t(t+2)/(t(t+2)+2), t = e^x  (exact identity)
__device__ __forceinline__ float mishf(float v) {
    float t = __expf(fminf(v, 20.f));
    float u = t * (t + 2.f);
    return v * (u / (u + 2.f));
}

// XCD-affinity decode: linear block L -> (xcd = L&7) owns batches b == xcd (mod 8).
__device__ __forceinline__ void xcd_decode(int L, int bpb, int& b, int& w) {
    int xcd = L & 7;
    int j   = L >> 3;
    b = xcd + 8 * (j / bpb);
    w = j - (j / bpb) * bpb;
}

// ---------------- K1: 1x1 conv 32->16 (high_fea -> padded in0 fp16) + weight transposes ----------------
// grid 768 = 48 b * 16 blocks; XCD-sharded. Round-5 proven inner form (chunk-prefetch spilled).
__global__ __launch_bounds__(256) void k_c0(const float* __restrict__ x,
                                            const float* __restrict__ W,
                                            const float* __restrict__ Wc1,
                                            const float* __restrict__ Wc2,
                                            const float* __restrict__ Wref,
                                            float* __restrict__ WTb,   // 1152 floats
                                            float* __restrict__ WTr,   // 2304 floats
                                            __half* __restrict__ out) {
    __shared__ float w[16*32];
    int tid = threadIdx.x;
    for (int i = tid; i < 512; i += 256) w[i] = W[i];
    if (blockIdx.x == 0) {
        for (int i = tid; i < 576; i += 256) {
            int co = i & 7; int t = i >> 3; int kyx = t % 9; int ci = t / 9;
            WTb[(ci*9 + kyx)*8 + co]       = Wc1[(co*8 + ci)*9 + kyx];
            WTb[576 + (ci*9 + kyx)*8 + co] = Wc2[(co*8 + ci)*9 + kyx];
        }
        for (int i = tid; i < 2304; i += 256) {
            int co = i & 7; int t = i >> 3; int kyx = t % 9; int cih = t / 9;  // 0..31
            int ci = cih & 15; int h = cih >> 4;
            WTr[((h*16 + ci)*9 + kyx)*8 + co] = Wref[((h*8 + co)*16 + ci)*9 + kyx];
        }
    }
    __syncthreads();
    int b, wblk;
    xcd_decode(blockIdx.x, 16, b, wblk);

    // zero pad rows 0,1,130,131 of all 16 channels for this batch (done by wblk==0)
    if (wblk == 0) {
        h4 z; z.a = __floats2half2_rn(0.f, 0.f); z.b = z.a;
        for (int i = tid; i < 2048; i += 256) {
            int ch = i >> 7;                 // 0..15
            int r4 = (i >> 5) & 3;           // 0..3
            int cc = (i & 31) << 2;          // 0..124
            int row = (r4 < 2) ? r4 : (r4 + 128);   // 0,1,130,131
            *(h4*)(out + (size_t)b*PCH + (size_t)ch*PHW + row*128 + cc) = z;
        }
    }

    int off = ((wblk*256 + tid) << 2);       // 4 px per thread
    const float* xb = x + (size_t)b * 32 * HW + off;
    float acc[16][4];
    #pragma unroll
    for (int c = 0; c < 16; ++c) { acc[c][0]=acc[c][1]=acc[c][2]=acc[c][3]=0.f; }
    #pragma unroll 8
    for (int ci = 0; ci < 32; ++ci) {
        float4 xv = *(const float4*)(xb + (size_t)ci * HW);
        #pragma unroll
        for (int co = 0; co < 16; ++co) {
            float wv = w[co*32 + ci];
            acc[co][0] += wv*xv.x; acc[co][1] += wv*xv.y;
            acc[co][2] += wv*xv.z; acc[co][3] += wv*xv.w;
        }
    }
    __half* ob = out + (size_t)b * PCH + 256 + off;   // +256 = 2 pad rows
    #pragma unroll
    for (int co = 0; co < 16; ++co)
        *(h4*)(ob + (size_t)co * PHW) = f4h(make_float4(acc[co][0],acc[co][1],acc[co][2],acc[co][3]));
}

// ---- direct 3x3 conv on PADDED fp16 input: 8 px/thread, 16B h8 loads, distance-2 prefetch ----
// Tile 128 wide x 8 tall, 128 threads. Window per (ci,ky): halfs [tx*8-8, tx*8+16) = 3 aligned
// h8 loads. Element x = tx*8 + D*(kx-1) + j -> u13 index k = 2 - D + D*kx + j (only halfs
// 6..18 of the window are consumed -> 13 cvt, not 24). Three buffer-groups A/B/C: group g's
// loads issue TWO full FMA-groups before use (~2x the latency coverage of round-5's schedule).
template<int D, int NCI>
__device__ __forceinline__ void dconv8h(const __half* __restrict__ base,  // padded, +2-row offset
                                        const float* __restrict__ wb,     // NCI*72 [ci][kyx][co8]
                                        const __half* __restrict__ zh,    // >=8 zeroed halfs (16B aligned)
                                        __half* __restrict__ obase,       // 8 ch planes (unpadded)
                                        float* __restrict__ statp,        // 2 floats
                                        int y0, int tid) {
    int tx = tid & 15, ty = tid >> 4;      // 16 x 8
    int y  = y0 + ty;
    int xg = tx*8 - 8;                     // leftmost loaded half (mult of 8 -> 16B aligned)
    bool mx0 = (tx > 0);                   // h8 @ xg
    bool mx2 = (tx < 15);                  // h8 @ xg+16

    float acc[8][8];
    #pragma unroll
    for (int c = 0; c < 8; ++c)
        #pragma unroll
        for (int j = 0; j < 8; ++j) acc[c][j] = 0.f;

    h8 A0,A1,A2, B0,B1,B2, C0,C1,C2;

    auto LD = [&](const __half* cb, int ky, h8& d0, h8& d1, h8& d2) {
        const __half* rp = cb + (y + D*(ky-1))*WW;
        d0 = *(const h8*)(mx0 ? rp      : zh);
        d1 = *(const h8*)(rp + 8);
        d2 = *(const h8*)(mx2 ? rp + 16 : zh);
    };
    auto FMAG = [&](const float* wp, const h8& v0, const h8& v1, const h8& v2) {
        float u[13];   // window halfs 6..18
        { float2 t = __half22float2(v0.d); u[0]=t.x;  u[1]=t.y; }
        { float2 t = __half22float2(v1.a); u[2]=t.x;  u[3]=t.y; }
        { float2 t = __half22float2(v1.b); u[4]=t.x;  u[5]=t.y; }
        { float2 t = __half22float2(v1.c); u[6]=t.x;  u[7]=t.y; }
        { float2 t = __half22float2(v1.d); u[8]=t.x;  u[9]=t.y; }
        { float2 t = __half22float2(v2.a); u[10]=t.x; u[11]=t.y; }
        { float2 t = __half22float2(v2.b); u[12]=t.x; }
        #pragma unroll
        for (int kx = 0; kx < 3; ++kx) {
            const float* wq = wp + kx*8;
            float w0 = wq[0], w1 = wq[1], w2 = wq[2], w3 = wq[3];
            float w4 = wq[4], w5 = wq[5], w6 = wq[6], w7 = wq[7];
            #pragma unroll
            for (int j = 0; j < 8; ++j) {
                float xv = u[2 - D + D*kx + j];
                acc[0][j] += w0*xv; acc[1][j] += w1*xv;
                acc[2][j] += w2*xv; acc[3][j] += w3*xv;
                acc[4][j] += w4*xv; acc[5][j] += w5*xv;
                acc[6][j] += w6*xv; acc[7][j] += w7*xv;
            }
        }
    };

    const __half* cb = base + xg;
    const float* wp = wb;
    LD(cb, 0, A0,A1,A2);
    LD(cb, 1, B0,B1,B2);
    #pragma unroll 1
    for (int ci = 0; ci < NCI; ++ci) {
        const __half* cbn = (ci + 1 < NCI) ? cb + PHW : cb;   // last iter: harmless reload
        LD(cb,  2, C0,C1,C2);
        FMAG(wp,      A0,A1,A2);
        LD(cbn, 0, A0,A1,A2);
        FMAG(wp + 24, B0,B1,B2);
        LD(cbn, 1, B0,B1,B2);
        FMAG(wp + 48, C0,C1,C2);
        cb = cbn; wp += 72;
    }

    // ---- write (fp16, unpadded) + GN partial stats (fp32) ----
    float s = 0.f, q = 0.f;
    __half* ob = obase + y*WW + tx*8;
    #pragma unroll
    for (int c = 0; c < 8; ++c) {
        h8 o;
        o.a = __floats2half2_rn(acc[c][0], acc[c][1]);
        o.b = __floats2half2_rn(acc[c][2], acc[c][3]);
        o.c = __floats2half2_rn(acc[c][4], acc[c][5]);
        o.d = __floats2half2_rn(acc[c][6], acc[c][7]);
        *(h8*)(ob + (size_t)c*HW) = o;
        #pragma unroll
        for (int j = 0; j < 8; ++j) { s += acc[c][j]; q += acc[c][j]*acc[c][j]; }
    }
    #pragma unroll
    for (int o = 32; o > 0; o >>= 1) { s += __shfl_down(s,o); q += __shfl_down(q,o); }
    if ((tid & 63) == 0) { atomicAdd(&statp[0], s); atomicAdd(&statp[1], q); }
}

// ---------------- K2: MERGED dual-branch 3x3 conv + low 1x1 conv; grid 3072 x 128 ----------------
// Per batch: 64 sub-blocks, parity-interleaved: even -> branch conv (latency-bound),
// odd -> low 1x1 (BW-bound). Complementary types co-resident per CU fill each other's bubbles.
__global__ __launch_bounds__(128) void k_bl(const __half* __restrict__ in0p,   // padded
                                            const float* __restrict__ WTb,
                                            const __half* __restrict__ zh,
                                            __half* __restrict__ hout,         // high_pre (unpadded)
                                            float* __restrict__ stat_br,       // 2/batch
                                            const float* __restrict__ xlow,
                                            const float* __restrict__ Wlow,
                                            __half* __restrict__ lout,         // low_pre (unpadded)
                                            float* __restrict__ stat_low) {    // 4/batch
    __shared__ float wsm[16*24];
    int tid = threadIdx.x;
    int b, w;
    xcd_decode(blockIdx.x, 64, b, w);
    int type = w & 1;
    int sub  = w >> 1;                      // 0..31

    if (type == 0) {
        // ---- branch conv: sub = br*16 + yblk ----
        int br = sub >> 4;
        int y0 = (sub & 15) << 3;
        if (br == 0) {
            dconv8h<1,8>(in0p + (size_t)b*PCH + 256,            WTb,       zh,
                         hout + (size_t)(b*16    )*HW, stat_br + b*2, y0, tid);
        } else {
            dconv8h<2,8>(in0p + (size_t)b*PCH + 8*(size_t)PHW + 256, WTb + 576, zh,
                         hout + (size_t)(b*16 + 8)*HW, stat_br + b*2, y0, tid);
        }
    } else {
        // ---- low 1x1 conv 24->16 + GN(groups=2) stats (round-5 inner form, 128 threads) ----
        for (int i = tid; i < 384; i += 128) wsm[i] = Wlow[i];
        __syncthreads();
        int off = ((sub*128 + tid) << 2);   // 512 px per sub-block
        const float* xb = xlow + (size_t)b * 24 * HW + off;
        float acc[16][4];
        #pragma unroll
        for (int c = 0; c < 16; ++c) { acc[c][0]=acc[c][1]=acc[c][2]=acc[c][3]=0.f; }
        #pragma unroll 8
        for (int ci = 0; ci < 24; ++ci) {
            float4 xv = *(const float4*)(xb + (size_t)ci * HW);
            #pragma unroll
            for (int co = 0; co < 16; ++co) {
                float wv = wsm[co*24 + ci];
                acc[co][0] += wv*xv.x; acc[co][1] += wv*xv.y;
                acc[co][2] += wv*xv.z; acc[co][3] += wv*xv.w;
            }
        }
        __half* ob = lout + (size_t)b * 16 * HW + off;
        float s0=0.f,q0=0.f,s1=0.f,q1=0.f;
        #pragma unroll
        for (int co = 0; co < 16; ++co) {
            *(h4*)(ob + (size_t)co * HW) = f4h(make_float4(acc[co][0],acc[co][1],acc[co][2],acc[co][3]));
            #pragma unroll
            for (int j = 0; j < 4; ++j) {
                if (co < 8) { s0 += acc[co][j]; q0 += acc[co][j]*acc[co][j]; }
                else        { s1 += acc[co][j]; q1 += acc[co][j]*acc[co][j]; }
            }
        }
        #pragma unroll
        for (int o = 32; o > 0; o >>= 1) {
            s0 += __shfl_down(s0,o); q0 += __shfl_down(q0,o);
            s1 += __shfl_down(s1,o); q1 += __shfl_down(q1,o);
        }
        if ((tid & 63) == 0) {
            atomicAdd(&stat_low[b*4+0], s0); atomicAdd(&stat_low[b*4+1], q0);
            atomicAdd(&stat_low[b*4+2], s1); atomicAdd(&stat_low[b*4+3], q1);
        }
    }
}

// ---------------- K4: GN-apply (high & low) + add + mish -> padded r; 8 px/thread ----------------
// grid 6144 = 48 b * 128 blocks
__global__ __launch_bounds__(256) void k_fuse(const __half* __restrict__ hp, const __half* __restrict__ lp,
                                              const float* __restrict__ gbn, const float* __restrict__ bbn,
                                              const float* __restrict__ glow, const float* __restrict__ blow,
                                              const float* __restrict__ sh, const float* __restrict__ sl,
                                              __half* __restrict__ r) {      // padded
    int b, wblk;
    xcd_decode(blockIdx.x, 128, b, wblk);
    int idx = wblk*256 + threadIdx.x;        // 0..32767 h8-groups within batch
    int p = b*262144 + (idx << 3);
    int c = idx >> 11;                       // channel 0..15
    int pxin = (idx << 3) & 16383;           // in-channel pixel offset
    float muh = sh[b*2] * (1.f/262144.f);
    float varh = sh[b*2+1]*(1.f/262144.f) - muh*muh;
    float rsh = rsqrtf(varh + EPS);
    int gi = b*4 + (c>>3)*2;
    float mul = sl[gi] * (1.f/131072.f);
    float varl = sl[gi+1]*(1.f/131072.f) - mul*mul;
    float rsl = rsqrtf(varl + EPS);
    float ga = gbn[c]*rsh, bh = bbn[c] - muh*ga;
    float gl = glow[c]*rsl, bl = blow[c] - mul*gl;
    h8 hv = *(const h8*)(hp + (size_t)p);
    h8 lv = *(const h8*)(lp + (size_t)p);
    float2 h01 = __half22float2(hv.a), h23 = __half22float2(hv.b),
           h45 = __half22float2(hv.c), h67 = __half22float2(hv.d);
    float2 l01 = __half22float2(lv.a), l23 = __half22float2(lv.b),
           l45 = __half22float2(lv.c), l67 = __half22float2(lv.d);
    float o0 = mishf(h01.x*ga + bh + l01.x*gl + bl);
    float o1 = mishf(h01.y*ga + bh + l01.y*gl + bl);
    float o2 = mishf(h23.x*ga + bh + l23.x*gl + bl);
    float o3 = mishf(h23.y*ga + bh + l23.y*gl + bl);
    float o4 = mishf(h45.x*ga + bh + l45.x*gl + bl);
    float o5 = mishf(h45.y*ga + bh + l45.y*gl + bl);
    float o6 = mishf(h67.x*ga + bh + l67.x*gl + bl);
    float o7 = mishf(h67.y*ga + bh + l67.y*gl + bl);
    h8 ov;
    ov.a = __floats2half2_rn(o0,o1); ov.b = __floats2half2_rn(o2,o3);
    ov.c = __floats2half2_rn(o4,o5); ov.d = __floats2half2_rn(o6,o7);
    *(h8*)(r + (size_t)b*PCH + (size_t)c*PHW + 256 + pxin) = ov;
}

// ---------------- K5: 3x3 conv 16->16 pad1 on padded r; grid 1536 x 128, XCD-sharded ----------------
// per batch: 32 blocks = 2 co-half * 16 yblk (8 rows each)
__global__ __launch_bounds__(128) void k_refp(const __half* __restrict__ rin,  // padded
                                              const float* __restrict__ WTr,
                                              const __half* __restrict__ zh,
                                              __half* __restrict__ outp,
                                              float* __restrict__ stat) {
    int b, w;
    xcd_decode(blockIdx.x, 32, b, w);
    int h  = w >> 4;
    int y0 = (w & 15) << 3;
    int tid = threadIdx.x;
    dconv8h<1,16>(rin + (size_t)b*PCH + 256, WTr + h*1152, zh,
                  outp + (size_t)(b*16 + h*8)*HW, stat + b*4 + h*2, y0, tid);
}

// ---------------- K6: GN-apply + mish + 1x1 seg conv 16->1; 8 px/thread, fp16 ----------------
// grid 384 = 48 b * 8 blocks
__global__ __launch_bounds__(256) void k_seg(const __half* __restrict__ rp,
                                             const float* __restrict__ gref, const float* __restrict__ bref,
                                             const float* __restrict__ wseg, const float* __restrict__ sr,
                                             __half* __restrict__ seg) {
    int b, wblk;
    xcd_decode(blockIdx.x, 8, b, wblk);
    int off = ((wblk*256 + threadIdx.x) << 3);   // 0..16376 within batch plane
    const __half* pb = rp + (size_t)b*16*HW + off;
    float a0=0,a1=0,a2=0,a3=0,a4=0,a5=0,a6=0,a7=0;
    #pragma unroll
    for (int c = 0; c < 16; ++c) {
        int gi = b*4 + (c>>3)*2;
        float mu = sr[gi] * (1.f/131072.f);
        float var = sr[gi+1]*(1.f/131072.f) - mu*mu;
        float rs = rsqrtf(var + EPS);
        float ga = gref[c]*rs, bb = bref[c] - mu*ga;
        float wv = wseg[c];
        h8 v = *(const h8*)(pb + (size_t)c*HW);
        float2 v01 = __half22float2(v.a), v23 = __half22float2(v.b),
               v45 = __half22float2(v.c), v67 = __half22float2(v.d);
        a0 += wv*mishf(v01.x*ga + bb); a1 += wv*mishf(v01.y*ga + bb);
        a2 += wv*mishf(v23.x*ga + bb); a3 += wv*mishf(v23.y*ga + bb);
        a4 += wv*mishf(v45.x*ga + bb); a5 += wv*mishf(v45.y*ga + bb);
        a6 += wv*mishf(v67.x*ga + bb); a7 += wv*mishf(v67.y*ga + bb);
    }
    h8 ov;
    ov.a = __floats2half2_rn(a0,a1); ov.b = __floats2half2_rn(a2,a3);
    ov.c = __floats2half2_rn(a4,a5); ov.d = __floats2half2_rn(a6,a7);
    *(h8*)(seg + (size_t)b*HW + off) = ov;
}

// ---------------- K7: bilinear x4 upsample + sigmoid (seg fp16 -> out fp32) ----------------
__global__ __launch_bounds__(256) void k_up(const __half* __restrict__ seg, float* __restrict__ out) {
    int i4 = blockIdx.x * 256 + threadIdx.x;    // 3,145,728 total
    int b = i4 / (512*128);
    int rem = i4 - b*(512*128);
    int y = rem >> 7; int k = rem & 127;
    const __half* sp = seg + (size_t)b * HW;
    float fy = fminf(fmaxf(0.25f*y - 0.375f, 0.f), 127.f);
    int y0 = min((int)fy, 126);
    float wy = fy - (float)y0;
    const __half* r0 = sp + y0*WW;
    const __half* r1 = r0 + WW;
    float res[4];
    #pragma unroll
    for (int j = 0; j < 4; ++j) {
        int x = k*4 + j;
        float fx = fminf(fmaxf(0.25f*x - 0.375f, 0.f), 127.f);
        int x0 = min((int)fx, 126);
        float wx = fx - (float)x0;
        float v0 = __half2float(r0[x0])*(1.f-wx) + __half2float(r0[x0+1])*wx;
        float v1 = __half2float(r1[x0])*(1.f-wx) + __half2float(r1[x0+1])*wx;
        float v = v0*(1.f-wy) + v1*wy;
        res[j] = 1.f/(1.f + __expf(-v));
    }
    *(float4*)(out + (size_t)i4*4) = make_float4(res[0],res[1],res[2],res[3]);
}

extern "C" void kernel_launch(void* const* d_in, const int* in_sizes, int n_in,
                              void* d_out, int out_size, void* d_ws, size_t ws_size,
                              hipStream_t stream) {
    const float* low  = (const float*)d_in[0];
    const float* high = (const float*)d_in[1];
    const float* Wc0  = (const float*)d_in[2];
    const float* Wc1  = (const float*)d_in[3];
    const float* Wc2  = (const float*)d_in[4];
    const float* gbn  = (const float*)d_in[5];
    const float* bbn  = (const float*)d_in[6];
    const float* Wlow = (const float*)d_in[7];
    const float* glow = (const float*)d_in[8];
    const float* blow = (const float*)d_in[9];
    const float* Wref = (const float*)d_in[10];
    const float* gref = (const float*)d_in[11];
    const float* bref = (const float*)d_in[12];
    const float* Wseg = (const float*)d_in[13];

    float* ws = (float*)d_ws;
    // A: PADDED fp16 tensor (in0, later r): 48*16*132*128 halfs = 26 MB, fits the 50 MB fp32 slot
    __half* A  = (__half*)ws;
    __half* Bb = (__half*)(ws + (size_t)SZ);         // high_pre, later ref_pre (unpadded)
    __half* C  = (__half*)(ws + 2*(size_t)SZ);       // low_pre (unpadded)
    __half* D  = (__half*)(ws + 3*(size_t)SZ);       // seg (48*16384 halfs)
    float* ST = ws + 3*(size_t)SZ + (size_t)48*HW;   // stats: 480 floats (zeroed each launch)
    float* ZB = ST + 480;                            // 64 zeroed floats: x-OOB redirect target
    float* WTb = ZB + 64;                            // 1152 floats
    float* WTr = WTb + 1152;                         // 2304 floats

    hipMemsetAsync(ST, 0, (480 + 64)*sizeof(float), stream);

    k_c0  <<<768,   256, 0, stream>>>(high, Wc0, Wc1, Wc2, Wref, WTb, WTr, A);
    k_bl  <<<3072,  128, 0, stream>>>(A, WTb, (const __half*)ZB, Bb, ST,
                                      low, Wlow, C, ST + 96);
    k_fuse<<<6144,  256, 0, stream>>>(Bb, C, gbn, bbn, glow, blow, ST, ST + 96, A);
    k_refp<<<1536,  128, 0, stream>>>(A, WTr, (const __half*)ZB, Bb, ST + 288);
    k_seg <<<384,   256, 0, stream>>>(Bb, gref, bref, Wseg, ST + 288, D);
    k_up  <<<12288, 256, 0, stream>>>(D, (float*)d_out);
}